// Round 5
// baseline (301.713 us; speedup 1.0000x reference)
//
#include <hip/hip_runtime.h>
#include <math.h>

#define BLOCK 256
// Layer cell counts (b=32, 3 anchors):
//  L0: 32*3*13*13 = 16224  -> 64 blocks   (13x13, anchors 6,7,8)
//  L1: 32*3*26*26 = 64896  -> 254 blocks  (26x26, anchors 3,4,5)
//  L2: 32*3*52*52 = 259584 -> 1014 blocks (52x52, anchors 0,1,2)
#define NB0 64
#define NB1 254
#define NB2 1014
#define NBLOCKS (NB0 + NB1 + NB2)

// anchors ordered [layer][a]: layer0 = ANCHORS[6,7,8], layer1 = [3,4,5], layer2 = [0,1,2]
__constant__ float c_anch[9][2] = {
    {116.f, 90.f}, {156.f, 198.f}, {373.f, 326.f},
    { 30.f, 61.f}, { 62.f,  45.f}, { 59.f, 119.f},
    { 10.f, 13.f}, { 16.f,  30.f}, { 33.f,  23.f}
};

// stable softplus: log(1+exp(x)) = max(x,0) + log(1+exp(-|x|))
__device__ __forceinline__ float softplusf(float x) {
    float ax = fabsf(x);
    return fmaxf(x, 0.f) + __logf(1.f + __expf(-ax));
}

__device__ __forceinline__ float sigmoidf(float x) {
    return __fdividef(1.f, 1.f + __expf(-x));
}

__global__ __launch_bounds__(BLOCK) void yolo_loss_main(
    const float* __restrict__ p0, const float* __restrict__ p1, const float* __restrict__ p2,
    const float* __restrict__ t0, const float* __restrict__ t1, const float* __restrict__ t2,
    const float* __restrict__ tgt, float* __restrict__ out)
{
    int blk = blockIdx.x;
    const float* pred;
    const float* tru;
    int layer, g, cells, bbase;
    if (blk < NB0)            { layer = 0; pred = p0; tru = t0; g = 13; cells = 16224;  bbase = 0; }
    else if (blk < NB0 + NB1) { layer = 1; pred = p1; tru = t1; g = 26; cells = 64896;  bbase = NB0; }
    else                      { layer = 2; pred = p2; tru = t2; g = 52; cells = 259584; bbase = NB0 + NB1; }

    const int tid  = threadIdx.x;
    const int w    = tid >> 6;        // wave id 0..3
    const int lane = tid & 63;
    const int cellbase = (blk - bbase) * BLOCK;
    const int wbase = cellbase + w * 64;     // this wave's first cell
    const int idx   = wbase + lane;
    const bool valid = idx < cells;

    // Wave-private LDS transpose slab: lds[w][c][cell], row stride 68.
    // Writes: addr%32 = (4c+cell)%32 -> exactly 2-way (free); reads stride-1 -> conflict-free.
    // NO __syncthreads needed: wave-synchronous, DS ops are in-order per wave.
    __shared__ float lds[4][16][68];

    const int hw = g * g;
    const float* pb = pred;
    float aw = 1.f, ah = 1.f, gx = 0.f, gy = 0.f;
    int b = 0;
    if (valid) {
        int ij = idx % hw;
        int a  = (idx / hw) % 3;
        b      = idx / (3 * hw);
        int i  = ij / g;
        int j  = ij - i * g;
        pb = pred + (size_t)((b * 3 + a) * 85) * hw + ij;   // channel stride hw, coalesced across lanes
        aw = c_anch[layer * 3 + a][0];
        ah = c_anch[layer * 3 + a][1];
        gx = (float)j; gy = (float)i;
    }
    const float gf = (float)g;

    // this wave's y_true region: 64 cells x 85 floats, contiguous
    const float* src = tru + (size_t)wbase * 85;

    float acc = 0.f;   // header losses
    float cls = 0.f;   // class bce sum (mask applied at end)
    float mask = 0.f;

    // ======== chunk 0: channels 0..15 (header 0..4 + classes 5..15) ========
#pragma unroll
    for (int k = 0; k < 16; k++) {
        int e  = k * 64 + lane;
        int cl = e >> 4, c = e & 15;      // c minor: 64B-contiguous per cell
        if (wbase + cl < cells)
            lds[w][c][cl] = src[(size_t)cl * 85 + c];
    }

    if (valid) {
        float y0 = lds[w][0][lane], y1 = lds[w][1][lane];
        float y2 = lds[w][2][lane], y3 = lds[w][3][lane];
        mask = lds[w][4][lane];

        float r0 = pb[0];
        float r1 = pb[hw];
        float r2 = pb[2 * hw];
        float r3 = pb[3 * hw];
        float r4 = pb[4 * hw];

        // ---- xy loss: bce(sigmoid(r), t) = softplus(r) - t*r ----
        float true_x = y0 * gf - gx;
        float true_y = y1 * gf - gy;
        float ls = 2.f - y2 * y3;
        float lxy = (softplusf(r0) - true_x * r0) + (softplusf(r1) - true_y * r1);
        acc += mask * ls * lxy;

        // ---- wh loss ----
        float tw = __logf(y2 * (416.f / aw));
        float th = __logf(y3 * (416.f / ah));
        float dw = r2 - tw, dh = r3 - th;
        acc += mask * ls * 0.5f * (dw * dw + dh * dh);

        // ---- conf bce + IoU-based neg mask ----
        float cbce = softplusf(r4) - mask * r4;
        float sx = sigmoidf(r0);
        float sy = sigmoidf(r1);
        float bx = __fdividef(sx + gx, gf);
        float by = __fdividef(sy + gy, gf);
        float bw = __expf(r2) * aw * (1.f / 416.f);
        float bh = __expf(r3) * ah * (1.f / 416.f);
        float a1 = bw * bh;
        float b1minx = bx - 0.5f * bw, b1maxx = bx + 0.5f * bw;
        float b1miny = by - 0.5f * bh, b1maxy = by + 0.5f * bh;

        const float* tg = tgt + b * 20 * 5;   // ~wave-uniform, L1-resident
        float best = 0.f;
#pragma unroll 4
        for (int k = 0; k < 20; k++) {
            float tx  = tg[k * 5 + 0];
            float ty  = tg[k * 5 + 1];
            float tww = tg[k * 5 + 2];
            float thh = tg[k * 5 + 3];
            float iw = fminf(b1maxx, tx + 0.5f * tww) - fmaxf(b1minx, tx - 0.5f * tww);
            float ih = fminf(b1maxy, ty + 0.5f * thh) - fmaxf(b1miny, ty - 0.5f * thh);
            iw = fmaxf(iw, 0.f);
            ih = fmaxf(ih, 0.f);
            float inter = iw * ih;
            float iou = __fdividef(inter, a1 + tww * thh - inter);
            best = fmaxf(best, iou);
        }
        float neg = (best < 0.5f) ? 1.f : 0.f;
        acc += mask * cbce + (1.f - mask) * neg * cbce;

        // classes living in chunk 0 (channels 5..15)
#pragma unroll
        for (int c = 5; c < 16; c++) {
            float x = pb[c * hw];
            float t = lds[w][c][lane];
            cls += softplusf(x) - t * x;
        }
    }

    // ======== chunks 1..4: channels 16..79 (fully unrolled -> cross-chunk scheduling) ========
#pragma unroll
    for (int c0 = 16; c0 < 80; c0 += 16) {
#pragma unroll
        for (int k = 0; k < 16; k++) {
            int e  = k * 64 + lane;
            int cl = e >> 4, c = e & 15;
            if (wbase + cl < cells)
                lds[w][c][cl] = src[(size_t)cl * 85 + c0 + c];
        }
        if (valid) {
#pragma unroll
            for (int c = 0; c < 16; c++) {
                float x = pb[(c0 + c) * hw];
                float t = lds[w][c][lane];
                cls += softplusf(x) - t * x;
            }
        }
    }

    // ======== tail: channels 80..84 (width 5) ========
#pragma unroll
    for (int k = 0; k < 5; k++) {
        int e  = k * 64 + lane;
        int cl = e / 5, c = e - cl * 5;
        if (wbase + cl < cells)
            lds[w][c][cl] = src[(size_t)cl * 85 + 80 + c];
    }
    if (valid) {
#pragma unroll
        for (int c = 0; c < 5; c++) {
            float x = pb[(80 + c) * hw];
            float t = lds[w][c][lane];
            cls += softplusf(x) - t * x;
        }
        acc += mask * cls;
    }

    // ---- block reduction: wave shuffle then LDS, one atomic per block ----
    for (int off = 32; off > 0; off >>= 1)
        acc += __shfl_down(acc, off, 64);
    __shared__ float sh[BLOCK / 64];
    if (lane == 0)
        sh[w] = acc;
    __syncthreads();
    if (tid == 0) {
        float s = 0.f;
        for (int wv = 0; wv < BLOCK / 64; wv++) s += sh[wv];
        atomicAdd(out, s);   // fp32 atomic; tolerance ~2% >> reassociation error
    }
}

extern "C" void kernel_launch(void* const* d_in, const int* in_sizes, int n_in,
                              void* d_out, int out_size, void* d_ws, size_t ws_size,
                              hipStream_t stream) {
    // setup_inputs() dict order is INTERLEAVED:
    //   d_in[0]=y_pred0, d_in[1]=y_true0, d_in[2]=y_pred1, d_in[3]=y_true1,
    //   d_in[4]=y_pred2, d_in[5]=y_true2, d_in[6]=target
    const float* p0  = (const float*)d_in[0];
    const float* t0  = (const float*)d_in[1];
    const float* p1  = (const float*)d_in[2];
    const float* t1  = (const float*)d_in[3];
    const float* p2  = (const float*)d_in[4];
    const float* t2  = (const float*)d_in[5];
    const float* tgt = (const float*)d_in[6];

    // d_out is poisoned to 0xAA before every timed launch — zero it, then accumulate.
    hipMemsetAsync(d_out, 0, sizeof(float), stream);
    yolo_loss_main<<<NBLOCKS, BLOCK, 0, stream>>>(p0, p1, p2, t0, t1, t2, tgt, (float*)d_out);
}

// Round 6
// 292.789 us; speedup vs baseline: 1.0305x; 1.0305x over previous
//
#include <hip/hip_runtime.h>
#include <math.h>

typedef float f4 __attribute__((ext_vector_type(4)));

// Grid: big blocks first for tail behavior.
//  L2 (52x52): 259584 cells = 1014 blocks * 256 cells (64 thr * 4 cells)
//  L1 (26x26):  64896 cells ->  254 blocks (last half-masked)
//  L0 (13x13):  16224 cells ->  254 blocks * 64 thr * 1 cell (scalar path)
#define NL2 1014
#define NL1 254
#define NL0 254
#define NBLOCKS (NL2 + NL1 + NL0)

__constant__ float c_anch[9][2] = {
    {116.f, 90.f}, {156.f, 198.f}, {373.f, 326.f},   // layer0 (13x13): ANCHORS[6,7,8]
    { 30.f, 61.f}, { 62.f,  45.f}, { 59.f, 119.f},   // layer1 (26x26): ANCHORS[3,4,5]
    { 10.f, 13.f}, { 16.f,  30.f}, { 33.f,  23.f}    // layer2 (52x52): ANCHORS[0,1,2]
};

// stable softplus: bce(sigmoid(x),t) = softplus(x) - t*x
__device__ __forceinline__ float softplusf(float x) {
    float ax = fabsf(x);
    return fmaxf(x, 0.f) + __logf(1.f + __expf(-ax));
}
__device__ __forceinline__ float sigmoidf(float x) {
    return __fdividef(1.f, 1.f + __expf(-x));
}

__global__ __launch_bounds__(64) void yolo_loss_main(
    const float* __restrict__ p0, const float* __restrict__ p1, const float* __restrict__ p2,
    const float* __restrict__ t0, const float* __restrict__ t1, const float* __restrict__ t2,
    const float* __restrict__ tgt, float* __restrict__ out)
{
    // one wave per block -> wave-private LDS, zero __syncthreads.
    // lds[c][cell]: row stride 260 dwords (1040 B, 16B-aligned rows).
    // scatter writes: bank = (4q+j)*260 + cell -> exactly 2-way across 64 lanes (free).
    // b128 reads: uniform row, 16B/lane stride -> conflict-free.
    __shared__ float lds[16][260];

    const int blk  = blockIdx.x;
    const int lane = threadIdx.x;
    float acc = 0.f;

    if (blk < NL2 + NL1) {
        // ================= vector path: 4 consecutive cells per thread =================
        const float* pred; const float* tru;
        int hw, cells, base, arow;
        int plane, ij0, cell0;
        float gf;
        float gxv[4], gyv[4];
        if (blk < NL2) {
            pred = p2; tru = t2; hw = 2704; cells = 259584; arow = 6; gf = 52.f;
            base  = blk * 256;
            cell0 = base + 4 * lane;
            plane = cell0 / 2704; ij0 = cell0 - plane * 2704;
#pragma unroll
            for (int s = 0; s < 4; s++) { int ij = ij0 + s; int i = ij / 52; gyv[s] = (float)i; gxv[s] = (float)(ij - i * 52); }
        } else {
            pred = p1; tru = t1; hw = 676; cells = 64896; arow = 3; gf = 26.f;
            base  = (blk - NL2) * 256;
            cell0 = base + 4 * lane;
            plane = cell0 / 676; ij0 = cell0 - plane * 676;
#pragma unroll
            for (int s = 0; s < 4; s++) { int ij = ij0 + s; int i = ij / 26; gyv[s] = (float)i; gxv[s] = (float)(ij - i * 26); }
        }
        // 3*hw % 4 == 0 and cells % 4 == 0  ->  (b, a, validity) uniform over the 4-group
        const bool valid = cell0 < cells;
        const int aIdx = plane % 3;
        const int bIdx = plane / 3;
        const float* pb = pred + (size_t)plane * 85 * hw + ij0;   // dword offset %4==0 -> 16B aligned
        const float aw = c_anch[arow + aIdx][0];
        const float ah = c_anch[arow + aIdx][1];
        const char* tbase = (const char*)tru + (size_t)base * 340;

        f4 clsv = {0.f, 0.f, 0.f, 0.f};
        float m4[4] = {0.f, 0.f, 0.f, 0.f};

        // ===== chunk 0: channels 0..15 (header 0..4 + classes 5..15) =====
#pragma unroll
        for (int k = 0; k < 16; k++) {
            int u = k * 64 + lane;
            int cell = u >> 2, q = u & 3;
            if (base + cell < cells) {
                f4 v = *(const f4*)(tbase + (size_t)cell * 340 + q * 16);  // misaligned-ok dwordx4
                lds[4*q+0][cell] = v.x;
                lds[4*q+1][cell] = v.y;
                lds[4*q+2][cell] = v.z;
                lds[4*q+3][cell] = v.w;
            }
        }
        if (valid) {
            f4 y0 = *(const f4*)&lds[0][4*lane];
            f4 y1 = *(const f4*)&lds[1][4*lane];
            f4 y2 = *(const f4*)&lds[2][4*lane];
            f4 y3 = *(const f4*)&lds[3][4*lane];
            f4 ym = *(const f4*)&lds[4][4*lane];
            f4 r0 = *(const f4*)(pb);
            f4 r1 = *(const f4*)(pb + (size_t)hw);
            f4 r2 = *(const f4*)(pb + 2*(size_t)hw);
            f4 r3 = *(const f4*)(pb + 3*(size_t)hw);
            f4 r4 = *(const f4*)(pb + 4*(size_t)hw);

            float cb[4], bminx[4], bmaxx[4], bminy[4], bmaxy[4], area[4], best[4];
#pragma unroll
            for (int s = 0; s < 4; s++) {
                float R0 = r0[s], R1 = r1[s], R2 = r2[s], R3 = r3[s], R4 = r4[s];
                float Y0 = y0[s], Y1 = y1[s], Y2 = y2[s], Y3 = y3[s], M = ym[s];
                m4[s] = M;
                float gx = gxv[s], gy = gyv[s];
                float tx = Y0 * gf - gx, ty = Y1 * gf - gy;
                float ls = 2.f - Y2 * Y3;
                acc += M * ls * ((softplusf(R0) - tx * R0) + (softplusf(R1) - ty * R1));
                float tw = __logf(Y2 * (416.f / aw));
                float th = __logf(Y3 * (416.f / ah));
                float dw = R2 - tw, dh = R3 - th;
                acc += M * ls * 0.5f * (dw * dw + dh * dh);
                cb[s] = softplusf(R4) - M * R4;
                float sx = sigmoidf(R0), sy = sigmoidf(R1);
                float bx = __fdividef(sx + gx, gf), by = __fdividef(sy + gy, gf);
                float bw = __expf(R2) * aw * (1.f / 416.f);
                float bh = __expf(R3) * ah * (1.f / 416.f);
                area[s]  = bw * bh;
                bminx[s] = bx - 0.5f * bw; bmaxx[s] = bx + 0.5f * bw;
                bminy[s] = by - 0.5f * bh; bmaxy[s] = by + 0.5f * bh;
                best[s]  = 0.f;
            }
            const float* tg = tgt + bIdx * 100;   // b uniform per thread (group aligned)
#pragma unroll 4
            for (int k = 0; k < 20; k++) {
                float tx = tg[5*k], ty = tg[5*k+1], tw = tg[5*k+2], th = tg[5*k+3];
                float tminx = tx - 0.5f * tw, tmaxx = tx + 0.5f * tw;
                float tminy = ty - 0.5f * th, tmaxy = ty + 0.5f * th;
                float a2 = tw * th;
#pragma unroll
                for (int s = 0; s < 4; s++) {
                    float iw = fmaxf(fminf(bmaxx[s], tmaxx) - fmaxf(bminx[s], tminx), 0.f);
                    float ih = fmaxf(fminf(bmaxy[s], tmaxy) - fmaxf(bminy[s], tminy), 0.f);
                    float inter = iw * ih;
                    best[s] = fmaxf(best[s], __fdividef(inter, area[s] + a2 - inter));
                }
            }
#pragma unroll
            for (int s = 0; s < 4; s++) {
                float neg = (best[s] < 0.5f) ? 1.f : 0.f;
                acc += m4[s] * cb[s] + (1.f - m4[s]) * neg * cb[s];
            }
            // classes 5..15 from chunk 0
#pragma unroll
            for (int c = 5; c < 16; c++) {
                f4 tv = *(const f4*)&lds[c][4*lane];
                f4 xv = *(const f4*)(pb + (size_t)c * hw);
                f4 sp;
                sp.x = softplusf(xv.x); sp.y = softplusf(xv.y);
                sp.z = softplusf(xv.z); sp.w = softplusf(xv.w);
                clsv += sp - tv * xv;
            }
        }

        // ===== chunks: channels 16..79 =====
        for (int cc = 16; cc < 80; cc += 16) {
            const char* tc = tbase + cc * 4;
#pragma unroll
            for (int k = 0; k < 16; k++) {
                int u = k * 64 + lane;
                int cell = u >> 2, q = u & 3;
                if (base + cell < cells) {
                    f4 v = *(const f4*)(tc + (size_t)cell * 340 + q * 16);
                    lds[4*q+0][cell] = v.x;
                    lds[4*q+1][cell] = v.y;
                    lds[4*q+2][cell] = v.z;
                    lds[4*q+3][cell] = v.w;
                }
            }
            if (valid) {
#pragma unroll
                for (int c = 0; c < 16; c++) {
                    f4 tv = *(const f4*)&lds[c][4*lane];
                    f4 xv = *(const f4*)(pb + (size_t)(cc + c) * hw);
                    f4 sp;
                    sp.x = softplusf(xv.x); sp.y = softplusf(xv.y);
                    sp.z = softplusf(xv.z); sp.w = softplusf(xv.w);
                    clsv += sp - tv * xv;
                }
            }
        }

        // ===== tail: channels 80..84 =====
        {
            const char* tc = tbase + 320;
#pragma unroll
            for (int k = 0; k < 20; k++) {
                int u = k * 64 + lane;            // 1280 = 256 cells * 5 ch
                int cell = u / 5, c = u - cell * 5;
                if (base + cell < cells)
                    lds[c][cell] = *(const float*)(tc + (size_t)cell * 340 + c * 4);
            }
            if (valid) {
#pragma unroll
                for (int c = 0; c < 5; c++) {
                    f4 tv = *(const f4*)&lds[c][4*lane];
                    f4 xv = *(const f4*)(pb + (size_t)(80 + c) * hw);
                    f4 sp;
                    sp.x = softplusf(xv.x); sp.y = softplusf(xv.y);
                    sp.z = softplusf(xv.z); sp.w = softplusf(xv.w);
                    clsv += sp - tv * xv;
                }
            }
        }

        if (valid)
            acc += m4[0]*clsv.x + m4[1]*clsv.y + m4[2]*clsv.z + m4[3]*clsv.w;

    } else {
        // ================= scalar path: layer 0 (13x13, hw=169 not 4-divisible) =================
        int t = (blk - NL2 - NL1) * 64 + lane;
        if (t < 16224) {
            int ij = t % 169;
            int a  = (t / 169) % 3;
            int b  = t / 507;
            int i  = ij / 13;
            int j  = ij - i * 13;
            const float* pb = p0 + (size_t)((b * 3 + a) * 85) * 169 + ij;
            const float* tb = t0 + (size_t)((b * 3 + a) * 169 + ij) * 85;

            float r0 = pb[0], r1 = pb[169], r2 = pb[338], r3 = pb[507], r4 = pb[676];
            float y0 = tb[0], y1 = tb[1], y2 = tb[2], y3 = tb[3], mask = tb[4];
            float aw = c_anch[a][0], ah = c_anch[a][1];
            float gx = (float)j, gy = (float)i;

            float tx = y0 * 13.f - gx, ty = y1 * 13.f - gy;
            float ls = 2.f - y2 * y3;
            acc += mask * ls * ((softplusf(r0) - tx * r0) + (softplusf(r1) - ty * r1));
            float tw = __logf(y2 * (416.f / aw));
            float th = __logf(y3 * (416.f / ah));
            float dw = r2 - tw, dh = r3 - th;
            acc += mask * ls * 0.5f * (dw * dw + dh * dh);
            float cbce = softplusf(r4) - mask * r4;

            float sx = sigmoidf(r0), sy = sigmoidf(r1);
            float bx = __fdividef(sx + gx, 13.f), by = __fdividef(sy + gy, 13.f);
            float bw = __expf(r2) * aw * (1.f / 416.f);
            float bh = __expf(r3) * ah * (1.f / 416.f);
            float a1 = bw * bh;
            float b1minx = bx - 0.5f * bw, b1maxx = bx + 0.5f * bw;
            float b1miny = by - 0.5f * bh, b1maxy = by + 0.5f * bh;
            const float* tg = tgt + b * 100;
            float bestv = 0.f;
#pragma unroll 4
            for (int k = 0; k < 20; k++) {
                float px = tg[5*k], py = tg[5*k+1], pw = tg[5*k+2], ph = tg[5*k+3];
                float iw = fmaxf(fminf(b1maxx, px + 0.5f*pw) - fmaxf(b1minx, px - 0.5f*pw), 0.f);
                float ih = fmaxf(fminf(b1maxy, py + 0.5f*ph) - fmaxf(b1miny, py - 0.5f*ph), 0.f);
                float inter = iw * ih;
                bestv = fmaxf(bestv, __fdividef(inter, a1 + pw * ph - inter));
            }
            float neg = (bestv < 0.5f) ? 1.f : 0.f;
            acc += mask * cbce + (1.f - mask) * neg * cbce;

            float cls = 0.f;
#pragma unroll 8
            for (int c = 0; c < 80; c++) {
                float x = pb[(5 + c) * 169];
                float tt = tb[5 + c];
                cls += softplusf(x) - tt * x;
            }
            acc += mask * cls;
        }
    }

    // ---- single-wave reduction + one atomic per block ----
#pragma unroll
    for (int off = 32; off > 0; off >>= 1)
        acc += __shfl_down(acc, off, 64);
    if (lane == 0)
        atomicAdd(out, acc);
}

extern "C" void kernel_launch(void* const* d_in, const int* in_sizes, int n_in,
                              void* d_out, int out_size, void* d_ws, size_t ws_size,
                              hipStream_t stream) {
    // setup_inputs() dict order is INTERLEAVED:
    //   d_in[0]=y_pred0, d_in[1]=y_true0, d_in[2]=y_pred1, d_in[3]=y_true1,
    //   d_in[4]=y_pred2, d_in[5]=y_true2, d_in[6]=target
    const float* p0  = (const float*)d_in[0];
    const float* t0  = (const float*)d_in[1];
    const float* p1  = (const float*)d_in[2];
    const float* t1  = (const float*)d_in[3];
    const float* p2  = (const float*)d_in[4];
    const float* t2  = (const float*)d_in[5];
    const float* tgt = (const float*)d_in[6];

    // d_out is poisoned to 0xAA before every timed launch — zero it, then accumulate.
    hipMemsetAsync(d_out, 0, sizeof(float), stream);
    yolo_loss_main<<<NBLOCKS, 64, 0, stream>>>(p0, p1, p2, t0, t1, t2, tgt, (float*)d_out);
}